// Round 9
// baseline (608.262 us; speedup 1.0000x reference)
//
#include <hip/hip_runtime.h>

#define NN 50000
#define NE 640000
#define NPAD 50176     // even; 196*256
#define SCAN_B 196     // ceil(NN/256)
#define OUT_CHUNKS 64
#define OUT_CE 10000   // 64*10000 = 640000
#define IN_CHUNKS 128
#define IN_CE 5000     // 128*5000 = 640000

typedef short bf16x8 __attribute__((ext_vector_type(8)));
typedef float f32x4 __attribute__((ext_vector_type(4)));

__device__ __forceinline__ unsigned short f2bf(float f) {
  unsigned int u = __float_as_uint(f);
  unsigned int r = (u + 0x7FFFu + ((u >> 16) & 1u)) >> 16;
  return (unsigned short)r;
}
__device__ __forceinline__ float bf2f(unsigned short h) {
  return __uint_as_float(((unsigned int)h) << 16);
}

typedef const __attribute__((address_space(1))) void* gptr_t;
typedef __attribute__((address_space(3))) void* lptr_t;
__device__ __forceinline__ void gload16(const void* g, void* l) {
  __builtin_amdgcn_global_load_lds((gptr_t)g, (lptr_t)l, 16, 0, 0);
}

// ---------------- LDS histogram: no global atomics ----------------
__global__ __launch_bounds__(256) void k_hist(const int* __restrict__ src,
                                              const int* __restrict__ dst,
                                              unsigned short* __restrict__ hist_out,
                                              unsigned short* __restrict__ hist_in) {
  __shared__ unsigned int h[NPAD / 2];
  int b = blockIdx.x, tid = threadIdx.x;
  for (int i = tid; i < NPAD / 2; i += 256) h[i] = 0;
  __syncthreads();
  if (b < OUT_CHUNKS) {
    int base = b * OUT_CE;
    for (int i = tid; i < OUT_CE; i += 256) {
      int n = src[base + i];
      atomicAdd(&h[n >> 1], (n & 1) ? 0x10000u : 1u);
    }
  } else {
    int base = (b - OUT_CHUNKS) * IN_CE;
    for (int i = tid; i < IN_CE; i += 256) {
      int n = dst[base + i];
      atomicAdd(&h[n >> 1], (n & 1) ? 0x10000u : 1u);
    }
  }
  __syncthreads();
  unsigned int* outp = (unsigned int*)((b < OUT_CHUNKS ? hist_out : hist_in) +
                                       (size_t)(b < OUT_CHUNKS ? b : b - OUT_CHUNKS) * NPAD);
  for (int i = tid; i < NPAD / 2; i += 256) outp[i] = h[i];
}

// ---------------- scan1: degree sums, norms, in-place chunk prefixes ----------------
__global__ __launch_bounds__(256) void k_scan1(const unsigned short* __restrict__ hist_out,
                                               unsigned short* __restrict__ hist_in,
                                               float* __restrict__ nsrc,
                                               float* __restrict__ ndst,
                                               int* __restrict__ in_cnt,
                                               int* __restrict__ bsum) {
  int t = threadIdx.x, n = blockIdx.x * 256 + t;
  int tot_in = 0;
  if (n < NN) {
    int od = 0;
#pragma unroll 8
    for (int c = 0; c < OUT_CHUNKS; ++c) od += hist_out[(size_t)c * NPAD + n];
    int pf = 0;
#pragma unroll 8
    for (int c = 0; c < IN_CHUNKS; ++c) {
      size_t idx = (size_t)c * NPAD + n;
      unsigned short v = hist_in[idx];
      hist_in[idx] = (unsigned short)pf;
      pf += v;
    }
    tot_in = pf;
    in_cnt[n] = tot_in;
    nsrc[n] = 1.0f / sqrtf((float)max(od, 1));
    ndst[n] = 1.0f / sqrtf((float)max(tot_in, 1));
  }
  int s = tot_in;
#pragma unroll
  for (int o = 32; o >= 1; o >>= 1) s += __shfl_down(s, o);
  __shared__ int ws4[4];
  if ((t & 63) == 0) ws4[t >> 6] = s;
  __syncthreads();
  if (t == 0) bsum[blockIdx.x] = ws4[0] + ws4[1] + ws4[2] + ws4[3];
}

// ---------------- scan3: row_start ----------------
__global__ __launch_bounds__(256) void k_scan3(const int* __restrict__ in_cnt,
                                               const int* __restrict__ bsum,
                                               int* __restrict__ row_start) {
  int b = blockIdx.x, t = threadIdx.x, lane = t & 63, w = t >> 6;
  __shared__ int wtot[4];
  __shared__ int sbase;
  {
    int v = (t < b) ? bsum[t] : 0;
#pragma unroll
    for (int o = 32; o >= 1; o >>= 1) v += __shfl_down(v, o);
    if (lane == 0) wtot[w] = v;
    __syncthreads();
    if (t == 0) sbase = wtot[0] + wtot[1] + wtot[2] + wtot[3];
    __syncthreads();
  }
  int i = b * 256 + t;
  int v = (i < NN) ? in_cnt[i] : 0;
  int sc = v;
#pragma unroll
  for (int o = 1; o < 64; o <<= 1) {
    int x = __shfl_up(sc, o);
    if (lane >= o) sc += x;
  }
  if (lane == 63) wtot[w] = sc;
  __syncthreads();
  int base = sbase;
  for (int j = 0; j < w; ++j) base += wtot[j];
  if (i < NN) row_start[i] = base + sc - v;
}

// ---------------- CSR fill: LDS re-histogram gives local rank, no atomics ----------------
__global__ __launch_bounds__(256) void k_fill(const int* __restrict__ src,
                                              const int* __restrict__ dst,
                                              const int* __restrict__ row_start,
                                              const unsigned short* __restrict__ prefix,
                                              int* __restrict__ col) {
  __shared__ unsigned int h[NPAD / 2];
  int c = blockIdx.x, tid = threadIdx.x;
  for (int i = tid; i < NPAD / 2; i += 256) h[i] = 0;
  __syncthreads();
  int base = c * IN_CE;
  for (int i = tid; i < IN_CE; i += 256) {
    int d = dst[base + i];
    unsigned int old = atomicAdd(&h[d >> 1], (d & 1) ? 0x10000u : 1u);
    int rank = (d & 1) ? (int)(old >> 16) : (int)(old & 0xFFFFu);
    col[row_start[d] + (int)prefix[(size_t)c * NPAD + d] + rank] = src[base + i];
  }
}

// ---------------- fused embed + weight prep (embed writes X_t sliced layout) ----------------
__global__ __launch_bounds__(256) void k_embed_prep(const float* __restrict__ nf,
                                                    const float* __restrict__ W,
                                                    const float* __restrict__ b,
                                                    const float* __restrict__ nsrc,
                                                    float* __restrict__ xt,
                                                    const float* __restrict__ Wg,
                                                    const float* __restrict__ Wo1,
                                                    unsigned short* __restrict__ wt) {
  int bid = blockIdx.x;
  if (bid < 25000) {
    int idx = bid * 256 + threadIdx.x;
    int n = idx >> 7, j = idx & 127;
    const float* f = nf + n * 4;
    float acc = b[j];
    acc += f[0] * W[j] + f[1] * W[128 + j] + f[2] * W[256 + j] + f[3] * W[384 + j];
    xt[(size_t)(j >> 4) * NN * 16 + (size_t)n * 16 + (j & 15)] = acc * nsrc[n];
  } else {
    int idx = (bid - 25000) * 256 + threadIdx.x;  // 4 * 16384
    int mat = idx >> 14, rem = idx & 16383;
    int k = rem >> 7, n = rem & 127;
    const float* Wsrc = (mat < 3) ? (Wg + mat * 16384) : Wo1;
    float v = Wsrc[k * 128 + n];
    unsigned short hi = f2bf(v);
    float lo = v - bf2f(hi);
    unsigned short* basep = wt + mat * 32768;
    basep[n * 128 + k] = hi;
    basep[16384 + n * 128 + k] = f2bf(lo);
  }
}

// ---------------- sliced SpMM: slice s gathers only its 3.2 MB X_t slice ----------------
// slice = blockIdx & 7 -> (empirical round-robin) all blocks of slice s run on
// XCD s, so the slice stays L2-resident. Correct regardless of mapping.
// Wave = 1 node: 16 edge slots x 4 lanes x float4; 4-deep unrolled masked loads.
__global__ __launch_bounds__(256) void k_spmm(const float* __restrict__ xt,
                                              unsigned short* __restrict__ ahi,
                                              unsigned short* __restrict__ alo,
                                              const int* __restrict__ col,
                                              const int* __restrict__ row_start,
                                              const int* __restrict__ in_cnt,
                                              const float* __restrict__ ndst) {
  int s = blockIdx.x & 7;
  int node = (blockIdx.x >> 3) * 4 + (threadIdx.x >> 6);
  int lane = threadIdx.x & 63;
  int slot = lane >> 2, sub = lane & 3;
  const float4* Xs = (const float4*)(xt + (size_t)s * NN * 16);  // [node][4]
  int start = row_start[node];
  int cnt = in_cnt[node];
  float4 acc = make_float4(0.f, 0.f, 0.f, 0.f);
  for (int base = 0; base < cnt; base += 64) {
    int m = min(cnt - base, 64);
    int ccol = (lane < m) ? col[start + base + lane] : 0;
    int mm = m - 1;
    int i0 = slot, i1 = slot + 16, i2 = slot + 32, i3 = slot + 48;
    int s0 = __shfl(ccol, min(i0, mm));
    int s1 = __shfl(ccol, min(i1, mm));
    int s2 = __shfl(ccol, min(i2, mm));
    int s3 = __shfl(ccol, min(i3, mm));
    float f0 = (i0 < m) ? 1.f : 0.f;
    float f1 = (i1 < m) ? 1.f : 0.f;
    float f2 = (i2 < m) ? 1.f : 0.f;
    float f3 = (i3 < m) ? 1.f : 0.f;
    float4 v0 = Xs[(size_t)s0 * 4 + sub];
    float4 v1 = Xs[(size_t)s1 * 4 + sub];
    float4 v2 = Xs[(size_t)s2 * 4 + sub];
    float4 v3 = Xs[(size_t)s3 * 4 + sub];
    acc.x = fmaf(f0, v0.x, acc.x); acc.y = fmaf(f0, v0.y, acc.y);
    acc.z = fmaf(f0, v0.z, acc.z); acc.w = fmaf(f0, v0.w, acc.w);
    acc.x = fmaf(f1, v1.x, acc.x); acc.y = fmaf(f1, v1.y, acc.y);
    acc.z = fmaf(f1, v1.z, acc.z); acc.w = fmaf(f1, v1.w, acc.w);
    acc.x = fmaf(f2, v2.x, acc.x); acc.y = fmaf(f2, v2.y, acc.y);
    acc.z = fmaf(f2, v2.z, acc.z); acc.w = fmaf(f2, v2.w, acc.w);
    acc.x = fmaf(f3, v3.x, acc.x); acc.y = fmaf(f3, v3.y, acc.y);
    acc.z = fmaf(f3, v3.z, acc.z); acc.w = fmaf(f3, v3.w, acc.w);
  }
  // reduce across the 16 edge slots (stride 4,8,16,32)
#pragma unroll
  for (int o = 4; o < 64; o <<= 1) {
    acc.x += __shfl_xor(acc.x, o);
    acc.y += __shfl_xor(acc.y, o);
    acc.z += __shfl_xor(acc.z, o);
    acc.w += __shfl_xor(acc.w, o);
  }
  if (lane < 4) {
    float nd = ndst[node];
    float v0 = acc.x * nd, v1 = acc.y * nd, v2 = acc.z * nd, v3 = acc.w * nd;
    ushort4 h, l;
    h.x = f2bf(v0); l.x = f2bf(v0 - bf2f(h.x));
    h.y = f2bf(v1); l.y = f2bf(v1 - bf2f(h.y));
    h.z = f2bf(v2); l.z = f2bf(v2 - bf2f(h.z));
    h.w = f2bf(v3); l.w = f2bf(v3 - bf2f(h.w));
    int off = node * 128 + s * 16 + sub * 4;
    *(ushort4*)(ahi + off) = h;
    *(ushort4*)(alo + off) = l;
  }
}

// ---------------- MFMA GEMM (bf16x3 split): out = relu(A @ Wt^T + bias) ----------------
// modes: 0 = write X_t sliced fp32 * nsrc, 1 = write bf16 hi/lo, 3 = fused final dot
__global__ __launch_bounds__(256) void k_gemm_mfma(
    const unsigned short* __restrict__ Ahi, const unsigned short* __restrict__ Alo,
    const unsigned short* __restrict__ Wth, const unsigned short* __restrict__ Wtl,
    const float* __restrict__ bias, float* __restrict__ outf,
    unsigned short* __restrict__ outhi, unsigned short* __restrict__ outlo,
    const float* __restrict__ nsrc, const float* __restrict__ W_o2,
    const float* __restrict__ b_o2, int M, int mode) {
  __shared__ unsigned short sm[2 * 64 * 128];  // Ah (16KB) then Al (16KB)
  __shared__ float smred[4][64];
  int tid = threadIdx.x;
  int lane = tid & 63, w = tid >> 6;
  int tile0 = blockIdx.x * 64;

  {
    int slot = lane & 15;
#pragma unroll
    for (int j = 0; j < 4; ++j) {
      int ldsoff = w * 4096 + j * 1024;
      int row = (ldsoff >> 8) + (lane >> 4);
      int grow = tile0 + row;
      if (grow > M - 1) grow = M - 1;
      size_t gsrc = (size_t)grow * 256 + (size_t)(((slot ^ (row & 7)) << 4));
      gload16((const char*)Ahi + gsrc, (char*)sm + ldsoff);
      gload16((const char*)Alo + gsrc, (char*)sm + 16384 + ldsoff);
    }
  }

  bf16x8 bh[2][4], bl[2][4];
  {
    int koff = (lane >> 4) * 8;
#pragma unroll
    for (int cf = 0; cf < 2; ++cf) {
      int n = w * 32 + cf * 16 + (lane & 15);
      const unsigned short* ph = Wth + (size_t)n * 128 + koff;
      const unsigned short* pl = Wtl + (size_t)n * 128 + koff;
#pragma unroll
      for (int kc = 0; kc < 4; ++kc) {
        bh[cf][kc] = *(const bf16x8*)(ph + kc * 32);
        bl[cf][kc] = *(const bf16x8*)(pl + kc * 32);
      }
    }
  }

  f32x4 acc[4][2] = {};
  __syncthreads();

  int r15 = lane & 15, kq = lane >> 4;
  for (int kc = 0; kc < 4; ++kc) {
    bf16x8 ah[4], al[4];
#pragma unroll
    for (int m = 0; m < 4; ++m) {
      int row = m * 16 + r15;
      int boff = row * 256 + ((((kc * 4 + kq) ^ (row & 7))) << 4);
      ah[m] = *(const bf16x8*)((const char*)sm + boff);
      al[m] = *(const bf16x8*)((const char*)sm + 16384 + boff);
    }
#pragma unroll
    for (int m = 0; m < 4; ++m)
#pragma unroll
      for (int cf = 0; cf < 2; ++cf) {
        acc[m][cf] = __builtin_amdgcn_mfma_f32_16x16x32_bf16(ah[m], bh[cf][kc], acc[m][cf], 0, 0, 0);
        acc[m][cf] = __builtin_amdgcn_mfma_f32_16x16x32_bf16(ah[m], bl[cf][kc], acc[m][cf], 0, 0, 0);
        acc[m][cf] = __builtin_amdgcn_mfma_f32_16x16x32_bf16(al[m], bh[cf][kc], acc[m][cf], 0, 0, 0);
      }
  }

  if (mode == 3) {
    float w2v[2], bv2[2];
#pragma unroll
    for (int cf = 0; cf < 2; ++cf) {
      int colg = w * 32 + cf * 16 + r15;
      w2v[cf] = W_o2[colg];
      bv2[cf] = bias[colg];
    }
#pragma unroll
    for (int m = 0; m < 4; ++m) {
#pragma unroll
      for (int i = 0; i < 4; ++i) {
        float p = fmaxf(acc[m][0][i] + bv2[0], 0.f) * w2v[0] +
                  fmaxf(acc[m][1][i] + bv2[1], 0.f) * w2v[1];
#pragma unroll
        for (int msk = 1; msk < 16; msk <<= 1) p += __shfl_xor(p, msk);
        if (r15 == 0) smred[w][m * 16 + kq * 4 + i] = p;
      }
    }
    __syncthreads();
    if (tid < 64) {
      int gr = tile0 + tid;
      if (gr < M)
        outf[gr] = smred[0][tid] + smred[1][tid] + smred[2][tid] + smred[3][tid] + b_o2[0];
    }
    return;
  }
#pragma unroll
  for (int cf = 0; cf < 2; ++cf) {
    int colg = w * 32 + cf * 16 + r15;
    float bv = bias[colg];
    int sl = colg >> 4, so = colg & 15;  // slice, offset (mode 0)
#pragma unroll
    for (int m = 0; m < 4; ++m) {
#pragma unroll
      for (int i = 0; i < 4; ++i) {
        int gr = tile0 + m * 16 + kq * 4 + i;
        if (gr < M) {
          float v = fmaxf(acc[m][cf][i] + bv, 0.f);
          if (mode == 0) {
            outf[(size_t)sl * NN * 16 + (size_t)gr * 16 + so] = v * nsrc[gr];
          } else {
            unsigned short h = f2bf(v);
            outhi[(size_t)gr * 128 + colg] = h;
            outlo[(size_t)gr * 128 + colg] = f2bf(v - bf2f(h));
          }
        }
      }
    }
  }
}

extern "C" void kernel_launch(void* const* d_in, const int* in_sizes, int n_in,
                              void* d_out, int out_size, void* d_ws, size_t ws_size,
                              hipStream_t stream) {
  const float* node_feats = (const float*)d_in[0];
  const int* src = (const int*)d_in[1];
  const int* dst = (const int*)d_in[2];
  const float* W_emb = (const float*)d_in[3];
  const float* b_emb = (const float*)d_in[4];
  const float* W_g = (const float*)d_in[5];
  const float* b_g = (const float*)d_in[6];
  const float* W_o1 = (const float*)d_in[7];
  const float* b_o1 = (const float*)d_in[8];
  const float* W_o2 = (const float*)d_in[9];
  const float* b_o2 = (const float*)d_in[10];
  float* out = (float*)d_out;

  // Workspace layout (bytes); hist_* alias X region (dead before embed writes X).
  char* ws = (char*)d_ws;
  int* in_cnt    = (int*)(ws + 0);                        // 200,704
  int* row_start = (int*)(ws + 200704);                   // 200,704
  float* nsrc    = (float*)(ws + 401408);                 // 200,704
  float* ndst    = (float*)(ws + 602112);                 // 200,704
  int* bsum      = (int*)(ws + 802816);                   // 1,024
  int* col       = (int*)(ws + 803840);                   // 2,560,000
  unsigned short* wt = (unsigned short*)(ws + 3363840);   // 262,144
  float* X       = (float*)(ws + 3625984);                // 25,600,000 (X_t sliced / Xu hi-lo)
  unsigned short* Xu = (unsigned short*)(ws + 3625984);
  unsigned short* hist_out = (unsigned short*)(ws + 3625984);            // in X
  unsigned short* hist_in  = (unsigned short*)(ws + 3625984 + 6422528);  // in X
  unsigned short* Ahi = (unsigned short*)(ws + 29225984); // 12,800,000
  unsigned short* Alo = (unsigned short*)(ws + 42025984); // 12,800,000 -> ends 54,825,984

  k_hist<<<OUT_CHUNKS + IN_CHUNKS, 256, 0, stream>>>(src, dst, hist_out, hist_in);
  k_scan1<<<SCAN_B, 256, 0, stream>>>(hist_out, hist_in, nsrc, ndst, in_cnt, bsum);
  k_scan3<<<SCAN_B, 256, 0, stream>>>(in_cnt, bsum, row_start);
  k_fill<<<IN_CHUNKS, 256, 0, stream>>>(src, dst, row_start, hist_in, col);
  k_embed_prep<<<25256, 256, 0, stream>>>(node_feats, W_emb, b_emb, nsrc, X,
                                          W_g, W_o1, wt);

  int gemm_grid = (NN + 63) / 64;
  int spmm_grid = (NN / 4) * 8;  // 8 slices
  for (int l = 0; l < 3; ++l) {
    k_spmm<<<spmm_grid, 256, 0, stream>>>(X, Ahi, Alo, col, row_start, in_cnt, ndst);
    unsigned short* wth = wt + l * 32768;
    unsigned short* wtl = wth + 16384;
    if (l < 2) {
      k_gemm_mfma<<<gemm_grid, 256, 0, stream>>>(Ahi, Alo, wth, wtl, b_g + l * 128,
                                                 X, nullptr, nullptr, nsrc,
                                                 nullptr, nullptr, NN, 0);
    } else {
      k_gemm_mfma<<<gemm_grid, 256, 0, stream>>>(Ahi, Alo, wth, wtl, b_g + l * 128,
                                                 nullptr, Xu, Xu + 6400000, nsrc,
                                                 nullptr, nullptr, NN, 1);
    }
  }
  k_gemm_mfma<<<gemm_grid, 256, 0, stream>>>(Xu, Xu + 6400000, wt + 3 * 32768,
                                             wt + 3 * 32768 + 16384, b_o1,
                                             out, nullptr, nullptr, nsrc,
                                             W_o2, b_o2, NN, 3);
}

// Round 10
// 363.322 us; speedup vs baseline: 1.6742x; 1.6742x over previous
//
#include <hip/hip_runtime.h>

#define NN 50000
#define NE 640000
#define NPAD 50176     // even; 196*256
#define SCAN_B 196     // ceil(NN/256)
#define OUT_CHUNKS 64
#define OUT_CE 10000   // 64*10000 = 640000
#define IN_CHUNKS 128
#define IN_CE 5000     // 128*5000 = 640000

typedef short bf16x8 __attribute__((ext_vector_type(8)));
typedef float f32x4 __attribute__((ext_vector_type(4)));

__device__ __forceinline__ unsigned short f2bf(float f) {
  unsigned int u = __float_as_uint(f);
  unsigned int r = (u + 0x7FFFu + ((u >> 16) & 1u)) >> 16;
  return (unsigned short)r;
}
__device__ __forceinline__ float bf2f(unsigned short h) {
  return __uint_as_float(((unsigned int)h) << 16);
}

typedef const __attribute__((address_space(1))) void* gptr_t;
typedef __attribute__((address_space(3))) void* lptr_t;
__device__ __forceinline__ void gload16(const void* g, void* l) {
  __builtin_amdgcn_global_load_lds((gptr_t)g, (lptr_t)l, 16, 0, 0);
}

// ---------------- LDS histogram: no global atomics ----------------
__global__ __launch_bounds__(256) void k_hist(const int* __restrict__ src,
                                              const int* __restrict__ dst,
                                              unsigned short* __restrict__ hist_out,
                                              unsigned short* __restrict__ hist_in) {
  __shared__ unsigned int h[NPAD / 2];
  int b = blockIdx.x, tid = threadIdx.x;
  for (int i = tid; i < NPAD / 2; i += 256) h[i] = 0;
  __syncthreads();
  if (b < OUT_CHUNKS) {
    int base = b * OUT_CE;
    for (int i = tid; i < OUT_CE; i += 256) {
      int n = src[base + i];
      atomicAdd(&h[n >> 1], (n & 1) ? 0x10000u : 1u);
    }
  } else {
    int base = (b - OUT_CHUNKS) * IN_CE;
    for (int i = tid; i < IN_CE; i += 256) {
      int n = dst[base + i];
      atomicAdd(&h[n >> 1], (n & 1) ? 0x10000u : 1u);
    }
  }
  __syncthreads();
  unsigned int* outp = (unsigned int*)((b < OUT_CHUNKS ? hist_out : hist_in) +
                                       (size_t)(b < OUT_CHUNKS ? b : b - OUT_CHUNKS) * NPAD);
  for (int i = tid; i < NPAD / 2; i += 256) outp[i] = h[i];
}

// ---------------- scan1: degree sums, norms, in-place chunk prefixes ----------------
__global__ __launch_bounds__(256) void k_scan1(const unsigned short* __restrict__ hist_out,
                                               unsigned short* __restrict__ hist_in,
                                               float* __restrict__ nsrc,
                                               float* __restrict__ ndst,
                                               int* __restrict__ in_cnt,
                                               int* __restrict__ bsum) {
  int t = threadIdx.x, n = blockIdx.x * 256 + t;
  int tot_in = 0;
  if (n < NN) {
    int od = 0;
#pragma unroll 8
    for (int c = 0; c < OUT_CHUNKS; ++c) od += hist_out[(size_t)c * NPAD + n];
    int pf = 0;
#pragma unroll 8
    for (int c = 0; c < IN_CHUNKS; ++c) {
      size_t idx = (size_t)c * NPAD + n;
      unsigned short v = hist_in[idx];
      hist_in[idx] = (unsigned short)pf;
      pf += v;
    }
    tot_in = pf;
    in_cnt[n] = tot_in;
    nsrc[n] = 1.0f / sqrtf((float)max(od, 1));
    ndst[n] = 1.0f / sqrtf((float)max(tot_in, 1));
  }
  int s = tot_in;
#pragma unroll
  for (int o = 32; o >= 1; o >>= 1) s += __shfl_down(s, o);
  __shared__ int ws4[4];
  if ((t & 63) == 0) ws4[t >> 6] = s;
  __syncthreads();
  if (t == 0) bsum[blockIdx.x] = ws4[0] + ws4[1] + ws4[2] + ws4[3];
}

// ---------------- scan3: row_start ----------------
__global__ __launch_bounds__(256) void k_scan3(const int* __restrict__ in_cnt,
                                               const int* __restrict__ bsum,
                                               int* __restrict__ row_start) {
  int b = blockIdx.x, t = threadIdx.x, lane = t & 63, w = t >> 6;
  __shared__ int wtot[4];
  __shared__ int sbase;
  {
    int v = (t < b) ? bsum[t] : 0;
#pragma unroll
    for (int o = 32; o >= 1; o >>= 1) v += __shfl_down(v, o);
    if (lane == 0) wtot[w] = v;
    __syncthreads();
    if (t == 0) sbase = wtot[0] + wtot[1] + wtot[2] + wtot[3];
    __syncthreads();
  }
  int i = b * 256 + t;
  int v = (i < NN) ? in_cnt[i] : 0;
  int sc = v;
#pragma unroll
  for (int o = 1; o < 64; o <<= 1) {
    int x = __shfl_up(sc, o);
    if (lane >= o) sc += x;
  }
  if (lane == 63) wtot[w] = sc;
  __syncthreads();
  int base = sbase;
  for (int j = 0; j < w; ++j) base += wtot[j];
  if (i < NN) row_start[i] = base + sc - v;
}

// ---------------- CSR fill: LDS re-histogram gives local rank, no atomics ----------------
__global__ __launch_bounds__(256) void k_fill(const int* __restrict__ src,
                                              const int* __restrict__ dst,
                                              const int* __restrict__ row_start,
                                              const unsigned short* __restrict__ prefix,
                                              int* __restrict__ col) {
  __shared__ unsigned int h[NPAD / 2];
  int c = blockIdx.x, tid = threadIdx.x;
  for (int i = tid; i < NPAD / 2; i += 256) h[i] = 0;
  __syncthreads();
  int base = c * IN_CE;
  for (int i = tid; i < IN_CE; i += 256) {
    int d = dst[base + i];
    unsigned int old = atomicAdd(&h[d >> 1], (d & 1) ? 0x10000u : 1u);
    int rank = (d & 1) ? (int)(old >> 16) : (int)(old & 0xFFFFu);
    col[row_start[d] + (int)prefix[(size_t)c * NPAD + d] + rank] = src[base + i];
  }
}

// ---------------- fused embed + weight prep ----------------
__global__ __launch_bounds__(256) void k_embed_prep(const float* __restrict__ nf,
                                                    const float* __restrict__ W,
                                                    const float* __restrict__ b,
                                                    const float* __restrict__ nsrc,
                                                    float* __restrict__ xs,
                                                    const float* __restrict__ Wg,
                                                    const float* __restrict__ Wo1,
                                                    unsigned short* __restrict__ wt) {
  int bid = blockIdx.x;
  if (bid < 25000) {
    int idx = bid * 256 + threadIdx.x;
    int n = idx >> 7, j = idx & 127;
    const float* f = nf + n * 4;
    float acc = b[j];
    acc += f[0] * W[j] + f[1] * W[128 + j] + f[2] * W[256 + j] + f[3] * W[384 + j];
    xs[idx] = acc * nsrc[n];
  } else {
    int idx = (bid - 25000) * 256 + threadIdx.x;  // 4 * 16384
    int mat = idx >> 14, rem = idx & 16383;
    int k = rem >> 7, n = rem & 127;
    const float* Wsrc = (mat < 3) ? (Wg + mat * 16384) : Wo1;
    float v = Wsrc[k * 128 + n];
    unsigned short hi = f2bf(v);
    float lo = v - bf2f(hi);
    unsigned short* basep = wt + mat * 32768;
    basep[n * 128 + k] = hi;
    basep[16384 + n * 128 + k] = f2bf(lo);
  }
}

// ---------------- SpMM: a[n] = ndst[n]*sum xs[src]; write bf16 hi/lo split ----------------
// masked 8-deep ILP: 8 float4 gathers in flight per lane (16 edges/iteration)
__global__ __launch_bounds__(256) void k_spmm(const float* __restrict__ xs,
                                              unsigned short* __restrict__ ahi,
                                              unsigned short* __restrict__ alo,
                                              const int* __restrict__ col,
                                              const int* __restrict__ row_start,
                                              const int* __restrict__ in_cnt,
                                              const float* __restrict__ ndst) {
  int node = blockIdx.x * 4 + (threadIdx.x >> 6);
  int lane = threadIdx.x & 63;
  int half = lane >> 5;
  int ql = lane & 31;
  int start = row_start[node];
  int cnt = in_cnt[node];
  float4 acc = make_float4(0.f, 0.f, 0.f, 0.f);
  const float4* X4 = (const float4*)xs;
  for (int base = 0; base < cnt; base += 64) {
    int m = min(cnt - base, 64);
    int ccol = (lane < m) ? col[start + base + lane] : 0;
    int mm = m - 1;
    for (int jj = 0; jj < m; jj += 16) {
      int s[8];
      float f[8];
      float4 v[8];
#pragma unroll
      for (int u = 0; u < 8; ++u) {
        int idx = jj + u * 2 + half;
        s[u] = __shfl(ccol, min(idx, mm));
        f[u] = (idx < m) ? 1.f : 0.f;
      }
#pragma unroll
      for (int u = 0; u < 8; ++u) v[u] = X4[(size_t)s[u] * 32 + ql];
#pragma unroll
      for (int u = 0; u < 8; ++u) {
        acc.x = fmaf(f[u], v[u].x, acc.x);
        acc.y = fmaf(f[u], v[u].y, acc.y);
        acc.z = fmaf(f[u], v[u].z, acc.z);
        acc.w = fmaf(f[u], v[u].w, acc.w);
      }
    }
  }
  acc.x += __shfl_down(acc.x, 32);
  acc.y += __shfl_down(acc.y, 32);
  acc.z += __shfl_down(acc.z, 32);
  acc.w += __shfl_down(acc.w, 32);
  if (half == 0) {
    float nd = ndst[node];
    float v0 = acc.x * nd, v1 = acc.y * nd, v2 = acc.z * nd, v3 = acc.w * nd;
    ushort4 h, l;
    h.x = f2bf(v0); l.x = f2bf(v0 - bf2f(h.x));
    h.y = f2bf(v1); l.y = f2bf(v1 - bf2f(h.y));
    h.z = f2bf(v2); l.z = f2bf(v2 - bf2f(h.z));
    h.w = f2bf(v3); l.w = f2bf(v3 - bf2f(h.w));
    *(ushort4*)(ahi + (size_t)node * 128 + ql * 4) = h;
    *(ushort4*)(alo + (size_t)node * 128 + ql * 4) = l;
  }
}

// ---------------- MFMA GEMM (bf16x3 split): out = relu(A @ Wt^T + bias) ----------------
// modes: 0 = write fp32 * nsrc (xs), 1 = write bf16 hi/lo, 3 = fused final dot with W_o2
__global__ __launch_bounds__(256) void k_gemm_mfma(
    const unsigned short* __restrict__ Ahi, const unsigned short* __restrict__ Alo,
    const unsigned short* __restrict__ Wth, const unsigned short* __restrict__ Wtl,
    const float* __restrict__ bias, float* __restrict__ outf,
    unsigned short* __restrict__ outhi, unsigned short* __restrict__ outlo,
    const float* __restrict__ nsrc, const float* __restrict__ W_o2,
    const float* __restrict__ b_o2, int M, int mode) {
  __shared__ unsigned short sm[2 * 64 * 128];  // Ah (16KB) then Al (16KB)
  __shared__ float smred[4][64];
  int tid = threadIdx.x;
  int lane = tid & 63, w = tid >> 6;
  int tile0 = blockIdx.x * 64;

  {
    int slot = lane & 15;
#pragma unroll
    for (int j = 0; j < 4; ++j) {
      int ldsoff = w * 4096 + j * 1024;
      int row = (ldsoff >> 8) + (lane >> 4);
      int grow = tile0 + row;
      if (grow > M - 1) grow = M - 1;
      size_t gsrc = (size_t)grow * 256 + (size_t)(((slot ^ (row & 7)) << 4));
      gload16((const char*)Ahi + gsrc, (char*)sm + ldsoff);
      gload16((const char*)Alo + gsrc, (char*)sm + 16384 + ldsoff);
    }
  }

  bf16x8 bh[2][4], bl[2][4];
  {
    int koff = (lane >> 4) * 8;
#pragma unroll
    for (int cf = 0; cf < 2; ++cf) {
      int n = w * 32 + cf * 16 + (lane & 15);
      const unsigned short* ph = Wth + (size_t)n * 128 + koff;
      const unsigned short* pl = Wtl + (size_t)n * 128 + koff;
#pragma unroll
      for (int kc = 0; kc < 4; ++kc) {
        bh[cf][kc] = *(const bf16x8*)(ph + kc * 32);
        bl[cf][kc] = *(const bf16x8*)(pl + kc * 32);
      }
    }
  }

  f32x4 acc[4][2] = {};
  __syncthreads();

  int r15 = lane & 15, kq = lane >> 4;
  for (int kc = 0; kc < 4; ++kc) {
    bf16x8 ah[4], al[4];
#pragma unroll
    for (int m = 0; m < 4; ++m) {
      int row = m * 16 + r15;
      int boff = row * 256 + ((((kc * 4 + kq) ^ (row & 7))) << 4);
      ah[m] = *(const bf16x8*)((const char*)sm + boff);
      al[m] = *(const bf16x8*)((const char*)sm + 16384 + boff);
    }
#pragma unroll
    for (int m = 0; m < 4; ++m)
#pragma unroll
      for (int cf = 0; cf < 2; ++cf) {
        acc[m][cf] = __builtin_amdgcn_mfma_f32_16x16x32_bf16(ah[m], bh[cf][kc], acc[m][cf], 0, 0, 0);
        acc[m][cf] = __builtin_amdgcn_mfma_f32_16x16x32_bf16(ah[m], bl[cf][kc], acc[m][cf], 0, 0, 0);
        acc[m][cf] = __builtin_amdgcn_mfma_f32_16x16x32_bf16(al[m], bh[cf][kc], acc[m][cf], 0, 0, 0);
      }
  }

  if (mode == 3) {
    float w2v[2], bv2[2];
#pragma unroll
    for (int cf = 0; cf < 2; ++cf) {
      int colg = w * 32 + cf * 16 + r15;
      w2v[cf] = W_o2[colg];
      bv2[cf] = bias[colg];
    }
#pragma unroll
    for (int m = 0; m < 4; ++m) {
#pragma unroll
      for (int i = 0; i < 4; ++i) {
        float p = fmaxf(acc[m][0][i] + bv2[0], 0.f) * w2v[0] +
                  fmaxf(acc[m][1][i] + bv2[1], 0.f) * w2v[1];
#pragma unroll
        for (int msk = 1; msk < 16; msk <<= 1) p += __shfl_xor(p, msk);
        if (r15 == 0) smred[w][m * 16 + kq * 4 + i] = p;
      }
    }
    __syncthreads();
    if (tid < 64) {
      int gr = tile0 + tid;
      if (gr < M)
        outf[gr] = smred[0][tid] + smred[1][tid] + smred[2][tid] + smred[3][tid] + b_o2[0];
    }
    return;
  }
#pragma unroll
  for (int cf = 0; cf < 2; ++cf) {
    int colg = w * 32 + cf * 16 + r15;
    float bv = bias[colg];
#pragma unroll
    for (int m = 0; m < 4; ++m) {
#pragma unroll
      for (int i = 0; i < 4; ++i) {
        int gr = tile0 + m * 16 + kq * 4 + i;
        if (gr < M) {
          float v = fmaxf(acc[m][cf][i] + bv, 0.f);
          if (mode == 0) {
            outf[(size_t)gr * 128 + colg] = v * nsrc[gr];
          } else {
            unsigned short h = f2bf(v);
            outhi[(size_t)gr * 128 + colg] = h;
            outlo[(size_t)gr * 128 + colg] = f2bf(v - bf2f(h));
          }
        }
      }
    }
  }
}

extern "C" void kernel_launch(void* const* d_in, const int* in_sizes, int n_in,
                              void* d_out, int out_size, void* d_ws, size_t ws_size,
                              hipStream_t stream) {
  const float* node_feats = (const float*)d_in[0];
  const int* src = (const int*)d_in[1];
  const int* dst = (const int*)d_in[2];
  const float* W_emb = (const float*)d_in[3];
  const float* b_emb = (const float*)d_in[4];
  const float* W_g = (const float*)d_in[5];
  const float* b_g = (const float*)d_in[6];
  const float* W_o1 = (const float*)d_in[7];
  const float* b_o1 = (const float*)d_in[8];
  const float* W_o2 = (const float*)d_in[9];
  const float* b_o2 = (const float*)d_in[10];
  float* out = (float*)d_out;

  // Workspace layout (bytes); hist_* alias X region (dead before embed writes X).
  char* ws = (char*)d_ws;
  int* in_cnt    = (int*)(ws + 0);                        // 200,704
  int* row_start = (int*)(ws + 200704);                   // 200,704
  float* nsrc    = (float*)(ws + 401408);                 // 200,704
  float* ndst    = (float*)(ws + 602112);                 // 200,704
  int* bsum      = (int*)(ws + 802816);                   // 1,024
  int* col       = (int*)(ws + 803840);                   // 2,560,000
  unsigned short* wt = (unsigned short*)(ws + 3363840);   // 262,144
  float* X       = (float*)(ws + 3625984);                // 25,600,000
  unsigned short* Xu = (unsigned short*)(ws + 3625984);
  unsigned short* hist_out = (unsigned short*)(ws + 3625984);            // in X
  unsigned short* hist_in  = (unsigned short*)(ws + 3625984 + 6422528);  // in X
  unsigned short* Ahi = (unsigned short*)(ws + 29225984); // 12,800,000
  unsigned short* Alo = (unsigned short*)(ws + 42025984); // 12,800,000 -> ends 54,825,984

  k_hist<<<OUT_CHUNKS + IN_CHUNKS, 256, 0, stream>>>(src, dst, hist_out, hist_in);
  k_scan1<<<SCAN_B, 256, 0, stream>>>(hist_out, hist_in, nsrc, ndst, in_cnt, bsum);
  k_scan3<<<SCAN_B, 256, 0, stream>>>(in_cnt, bsum, row_start);
  k_fill<<<IN_CHUNKS, 256, 0, stream>>>(src, dst, row_start, hist_in, col);
  k_embed_prep<<<25256, 256, 0, stream>>>(node_feats, W_emb, b_emb, nsrc, X,
                                          W_g, W_o1, wt);

  int gemm_grid = (NN + 63) / 64;
  for (int l = 0; l < 3; ++l) {
    k_spmm<<<NN / 4, 256, 0, stream>>>(X, Ahi, Alo, col, row_start, in_cnt, ndst);
    unsigned short* wth = wt + l * 32768;
    unsigned short* wtl = wth + 16384;
    if (l < 2) {
      k_gemm_mfma<<<gemm_grid, 256, 0, stream>>>(Ahi, Alo, wth, wtl, b_g + l * 128,
                                                 X, nullptr, nullptr, nsrc,
                                                 nullptr, nullptr, NN, 0);
    } else {
      k_gemm_mfma<<<gemm_grid, 256, 0, stream>>>(Ahi, Alo, wth, wtl, b_g + l * 128,
                                                 nullptr, Xu, Xu + 6400000, nsrc,
                                                 nullptr, nullptr, NN, 1);
    }
  }
  k_gemm_mfma<<<gemm_grid, 256, 0, stream>>>(Xu, Xu + 6400000, wt + 3 * 32768,
                                             wt + 3 * 32768 + 16384, b_o1,
                                             out, nullptr, nullptr, nsrc,
                                             W_o2, b_o2, NN, 3);
}